// Round 9
// baseline (198.094 us; speedup 1.0000x reference)
//
#include <hip/hip_runtime.h>
#include <hip/hip_bf16.h>
#include <math.h>

#define BB 8
#define MM 8192
#define DD 512
#define RR 64
#define HH 128

typedef __attribute__((ext_vector_type(8))) short bf16x8;
typedef __attribute__((ext_vector_type(4))) short bf16x4;
typedef __attribute__((ext_vector_type(4))) float f32x4;

#define XN_LD 520   // bf16 elems per xn row (512 + 8 pad)
#define H_LD  136   // bf16 elems per h row  (128 + 8 pad)

__device__ __forceinline__ float gelu_tanh(float x) {
    float u = 0.7978845608028654f * (x + 0.044715f * x * x * x);
    float e = __expf(2.0f * u);
    float t = 1.0f - 2.0f / (e + 1.0f);   // tanh(u)
    return 0.5f * x * (1.0f + t);
}

__device__ __forceinline__ short f2bf(float f) {   // round-to-nearest-even bf16
    unsigned int u = __float_as_uint(f);
    unsigned int r = u + 0x7FFFu + ((u >> 16) & 1u);
    return (short)(r >> 16);
}

// ---------------- prep: transpose-convert weights to bf16 [N][K] ----------------
__global__ __launch_bounds__(256) void prep_weights_kernel(
    const float* __restrict__ We1, const float* __restrict__ We2,
    short* __restrict__ We1T, short* __restrict__ We2T)
{
    int idx = blockIdx.x * 256 + threadIdx.x;
    if (idx < 128 * 512) {           // We1T[n][k] = bf16(We1[k][n])
        int n = idx >> 9, k = idx & 511;
        We1T[idx] = f2bf(We1[k * HH + n]);
    } else {
        int j = idx - 128 * 512;
        if (j < 64 * 128) {          // We2T[n][k] = bf16(We2[k][n])
            int n = j >> 7, k = j & 127;
            We2T[j] = f2bf(We2[k * RR + n]);
        }
    }
}

// ---------------- Kernel A: add path (512 rows, tiny, fp32) ----------------
__global__ __launch_bounds__(256) void add_path_kernel(
    const float* __restrict__ ot, const float* __restrict__ scale,
    const float* __restrict__ bias, const float* __restrict__ Wa1,
    const float* __restrict__ ba1, const float* __restrict__ Wa2,
    const float* __restrict__ ba2, float* __restrict__ add_out)
{
    int tid = threadIdx.x;
    int b = blockIdx.x >> 6, r = blockIdx.x & 63;
    const float* x = ot + (size_t)(b * RR + r) * DD;
    __shared__ float xs[DD];
    __shared__ float hsm[HH];
    __shared__ float rs[4], rq[4];
    float v0 = x[tid], v1 = x[tid + 256];
    float s = v0 + v1, q = v0 * v0 + v1 * v1;
    #pragma unroll
    for (int off = 32; off > 0; off >>= 1) { s += __shfl_xor(s, off); q += __shfl_xor(q, off); }
    if ((tid & 63) == 0) { rs[tid >> 6] = s; rq[tid >> 6] = q; }
    __syncthreads();
    s = rs[0] + rs[1] + rs[2] + rs[3];
    q = rq[0] + rq[1] + rq[2] + rq[3];
    float mean = s * (1.0f / DD);
    float var = q * (1.0f / DD) - mean * mean;
    float inv = rsqrtf(var + 1e-6f);
    xs[tid]       = (v0 - mean) * inv * scale[tid]       + bias[tid];
    xs[tid + 256] = (v1 - mean) * inv * scale[tid + 256] + bias[tid + 256];
    __syncthreads();
    if (tid < HH) {
        float acc = ba1[tid];
        for (int k = 0; k < DD; k++) acc = fmaf(xs[k], Wa1[k * HH + tid], acc);
        hsm[tid] = gelu_tanh(acc);
    }
    __syncthreads();
    int d0 = tid, d1 = tid + 256;
    float a0 = ba2[d0], a1 = ba2[d1];
    #pragma unroll 4
    for (int k = 0; k < HH; k++) {
        float hk = hsm[k];
        a0 = fmaf(hk, Wa2[k * DD + d0], a0);
        a1 = fmaf(hk, Wa2[k * DD + d1], a1);
    }
    add_out[(size_t)(b * RR + r) * DD + d0] = a0;
    add_out[(size_t)(b * RR + r) * DD + d1] = a1;
}

// ---------------- erase v4b: 512 threads / 8 waves per 32-row block ----------
// Fixed LN coverage: 16 threads/row x 8 float4 = 512 floats per row.
__global__ __launch_bounds__(512) void erase_mfma_kernel(
    const float* __restrict__ mem, const float* __restrict__ scale,
    const float* __restrict__ bias, const short* __restrict__ We1T,
    const float* __restrict__ be1, const short* __restrict__ We2T,
    const float* __restrict__ be2, float* __restrict__ logits,
    float* __restrict__ pmax, float* __restrict__ psum)
{
    __shared__ short xn[32 * XN_LD];     // 33,280 B; hsm overlays after GEMM1
    short* hsm = xn;

    int tid = threadIdx.x;
    int b = blockIdx.x >> 8;
    int chunk = blockIdx.x & 255;
    int m0 = chunk * 32;

    // ---- LN: 16 threads per row, 8 independent float4 loads per thread ----
    {
        int row = tid >> 4, sub = tid & 15;
        const float4* srcv = (const float4*)(mem + (size_t)(b * MM + m0 + row) * DD);
        float4 v[8];
        #pragma unroll
        for (int j = 0; j < 8; j++) v[j] = srcv[j * 16 + sub];
        float s = 0.f, q = 0.f;
        #pragma unroll
        for (int j = 0; j < 8; j++) {
            s += v[j].x + v[j].y + v[j].z + v[j].w;
            q += v[j].x*v[j].x + v[j].y*v[j].y + v[j].z*v[j].z + v[j].w*v[j].w;
        }
        #pragma unroll
        for (int off = 1; off <= 8; off <<= 1) { s += __shfl_xor(s, off); q += __shfl_xor(q, off); }
        float mean = s * (1.0f / 512.0f);
        float var = q * (1.0f / 512.0f) - mean * mean;
        float inv = rsqrtf(var + 1e-6f);
        const float4* scv = (const float4*)scale;
        const float4* biv = (const float4*)bias;
        #pragma unroll
        for (int j = 0; j < 8; j++) {
            float4 sc = scv[j * 16 + sub], bi = biv[j * 16 + sub];
            bf16x4 o;
            o[0] = f2bf((v[j].x - mean) * inv * sc.x + bi.x);
            o[1] = f2bf((v[j].y - mean) * inv * sc.y + bi.y);
            o[2] = f2bf((v[j].z - mean) * inv * sc.z + bi.z);
            o[3] = f2bf((v[j].w - mean) * inv * sc.w + bi.w);
            *(bf16x4*)&xn[row * XN_LD + (j * 16 + sub) * 4] = o;
        }
    }
    __syncthreads();

    int w = tid >> 6, l = tid & 63;
    int lr = l & 15, g = l >> 4, kg = g * 8;

    // ---- GEMM1: wave w owns col-frag w (cols w*16..+15), rows 0..31 ----
    const short* bp0 = We1T + ((size_t)(w * 16 + lr) << 9) + kg;
    f32x4 acc0 = {0.f,0.f,0.f,0.f}, acc1 = acc0;
    #pragma unroll 4
    for (int ks = 0; ks < 16; ks++) {
        int k0 = ks * 32;
        bf16x8 a0 = *(const bf16x8*)&xn[lr * XN_LD + k0 + kg];
        bf16x8 a1 = *(const bf16x8*)&xn[(16 + lr) * XN_LD + k0 + kg];
        bf16x8 b0 = *(const bf16x8*)(bp0 + k0);
        acc0 = __builtin_amdgcn_mfma_f32_16x16x32_bf16(a0, b0, acc0, 0, 0, 0);
        acc1 = __builtin_amdgcn_mfma_f32_16x16x32_bf16(a1, b0, acc1, 0, 0, 0);
    }
    __syncthreads();   // WAR: all waves done reading xn before hsm overlay writes
    {
        int col = w * 16 + lr;
        float bv = be1[col];
        #pragma unroll
        for (int rg = 0; rg < 4; rg++) {
            hsm[(g * 4 + rg) * H_LD + col]      = f2bf(gelu_tanh(acc0[rg] + bv));
            hsm[(16 + g * 4 + rg) * H_LD + col] = f2bf(gelu_tanh(acc1[rg] + bv));
        }
    }
    __syncthreads();

    // ---- GEMM2: wave w -> m-half (w&1), col-frag (w>>1) ----
    int mhalf = w & 1, nf2 = w >> 1;
    const short* bp2 = We2T + (nf2 * 16 + lr) * 128 + kg;
    f32x4 c0 = {0.f,0.f,0.f,0.f};
    #pragma unroll
    for (int ks = 0; ks < 4; ks++) {
        bf16x8 a2 = *(const bf16x8*)&hsm[(mhalf * 16 + lr) * H_LD + ks * 32 + kg];
        bf16x8 bb = *(const bf16x8*)(bp2 + ks * 32);
        c0 = __builtin_amdgcn_mfma_f32_16x16x32_bf16(a2, bb, c0, 0, 0, 0);
    }
    // ---- +bias, store logits, per-16-row-column (max,sumexp) ----
    {
        int c = nf2 * 16 + lr;
        float bv = be2[c];
        float vv[4];
        #pragma unroll
        for (int rg = 0; rg < 4; rg++) {
            vv[rg] = c0[rg] + bv;
            logits[(size_t)(b * MM + m0 + mhalf * 16 + g * 4 + rg) * 64 + c] = vv[rg];
        }
        float mx = fmaxf(fmaxf(vv[0], vv[1]), fmaxf(vv[2], vv[3]));
        float sm = __expf(vv[0] - mx) + __expf(vv[1] - mx)
                 + __expf(vv[2] - mx) + __expf(vv[3] - mx);
        #pragma unroll
        for (int off = 16; off <= 32; off <<= 1) {
            float om = __shfl_xor(mx, off);
            float os = __shfl_xor(sm, off);
            float nm = fmaxf(mx, om);
            sm = sm * __expf(mx - nm) + os * __expf(om - nm);
            mx = nm;
        }
        if (l < 16) {
            int ch2 = chunk * 2 + mhalf;           // 16-row chunk id: 0..511
            pmax[((size_t)b * 512 + ch2) * 64 + c] = mx;
            psum[((size_t)b * 512 + ch2) * 64 + c] = sm;
        }
    }
}

// ---------------- combine 512 chunk partials -> rmax, rinv ------------------
__global__ __launch_bounds__(256) void softmax_finalize_kernel(
    const float* __restrict__ pmax, const float* __restrict__ psum,
    float* __restrict__ rmax, float* __restrict__ rinv)
{
    int b = blockIdx.x;
    int g = threadIdx.x >> 6, r = threadIdx.x & 63;
    float mx = -1e30f, sm = 0.0f;
    for (int ch = g; ch < 512; ch += 4) {
        float m2 = pmax[((size_t)b * 512 + ch) * 64 + r];
        float s2 = psum[((size_t)b * 512 + ch) * 64 + r];
        float nm = fmaxf(mx, m2);
        sm = sm * __expf(mx - nm) + s2 * __expf(m2 - nm);
        mx = nm;
    }
    __shared__ float sx_[4][64], sm_[4][64];
    sx_[g][r] = mx; sm_[g][r] = sm;
    __syncthreads();
    if (threadIdx.x < 64) {
        float M_ = sx_[0][threadIdx.x], S_ = sm_[0][threadIdx.x];
        #pragma unroll
        for (int gg = 1; gg < 4; gg++) {
            float m2 = sx_[gg][threadIdx.x], s2 = sm_[gg][threadIdx.x];
            float nm = fmaxf(M_, m2);
            S_ = S_ * __expf(M_ - nm) + s2 * __expf(m2 - nm);
            M_ = nm;
        }
        rmax[b * 64 + threadIdx.x] = M_;
        rinv[b * 64 + threadIdx.x] = 1.0f / S_;
    }
}

// ---------------- scale+transpose add -> addT[b][d][r] bf16 (rinv folded in) ----------
__global__ __launch_bounds__(256) void scale_transpose_kernel(
    const float* __restrict__ add, const float* __restrict__ rinv,
    short* __restrict__ addT)
{
    int b = blockIdx.x >> 3;
    int part = blockIdx.x & 7;
    const float* rv = rinv + b * 64;
    #pragma unroll
    for (int i = 0; i < 16; i++) {
        int idx = part * 4096 + threadIdx.x + i * 256;   // 0..32767
        int d = idx >> 6, r = idx & 63;
        addT[(size_t)b * 32768 + idx] =
            f2bf(add[((size_t)b * 64 + r) * 512 + d] * rv[r]);
    }
}

// ---------------- apply (validated layout; 32-row blocks for 2x grid TLP) ------------
__global__ __launch_bounds__(256, 4) void apply_mfma_kernel(
    const float* __restrict__ mem, const float* __restrict__ logits,
    const short* __restrict__ addT, const float* __restrict__ rmax,
    float* __restrict__ out)
{
    int tid = threadIdx.x;
    int w = tid >> 6, l = tid & 63;
    int b = blockIdx.x >> 8;
    int mt = blockIdx.x & 255;
    int m0 = mt * 32;
    int lr = l & 15, kg = (l >> 4) * 8;
    int nbase = w * 128;
    const short* aT = addT + (size_t)b * 512 * 64;

    float rm0[8], rm1[8];
    #pragma unroll
    for (int j = 0; j < 8; j++) {
        rm0[j] = rmax[b * 64 + kg + j];
        rm1[j] = rmax[b * 64 + 32 + kg + j];
    }

    for (int ms = 0; ms < 2; ms++) {
        // ---- prefetch the 32 mem scalars this lane blends in this ms-iter ----
        float mv[8][4];
        #pragma unroll
        for (int nf = 0; nf < 8; nf++) {
            int d = nbase + nf * 16 + lr;
            #pragma unroll
            for (int rg = 0; rg < 4; rg++) {
                int m = m0 + ms * 16 + (l >> 4) * 4 + rg;
                mv[nf][rg] = mem[(size_t)(b * MM + m) * DD + d];
            }
        }
        // ---- weights: exp(logit - rmax), pack bf16 ----
        int mrow = m0 + ms * 16 + lr;
        const float* lp = logits + (size_t)(b * MM + mrow) * 64 + kg;
        float w0[8], w1[8];
        #pragma unroll
        for (int j = 0; j < 8; j++) {
            w0[j] = __expf(lp[j]      - rm0[j]);
            w1[j] = __expf(lp[32 + j] - rm1[j]);
        }
        bf16x8 a0, a1;
        #pragma unroll
        for (int j = 0; j < 8; j++) { a0[j] = f2bf(w0[j]); a1[j] = f2bf(w1[j]); }

        f32x4 acc[8];
        #pragma unroll
        for (int nf = 0; nf < 8; nf++) {
            int d = nbase + nf * 16 + lr;
            bf16x8 b0 = *(const bf16x8*)&aT[d * 64 + kg];
            bf16x8 b1 = *(const bf16x8*)&aT[d * 64 + 32 + kg];
            f32x4 c = (f32x4){0.f, 0.f, 0.f, 0.f};
            c = __builtin_amdgcn_mfma_f32_16x16x32_bf16(a0, b0, c, 0, 0, 0);
            c = __builtin_amdgcn_mfma_f32_16x16x32_bf16(a1, b1, c, 0, 0, 0);
            acc[nf] = c;
        }
        // ---- epilogue: out = mem + ea*(1-mem) (mem already in regs) ----
        #pragma unroll
        for (int nf = 0; nf < 8; nf++) {
            int d = nbase + nf * 16 + lr;
            #pragma unroll
            for (int rg = 0; rg < 4; rg++) {
                int m = m0 + ms * 16 + (l >> 4) * 4 + rg;
                size_t off = (size_t)(b * MM + m) * DD + d;
                float mvv = mv[nf][rg];
                out[off] = fmaf(acc[nf][rg], 1.0f - mvv, mvv);
            }
        }
    }
}

extern "C" void kernel_launch(void* const* d_in, const int* in_sizes, int n_in,
                              void* d_out, int out_size, void* d_ws, size_t ws_size,
                              hipStream_t stream) {
    const float* memory = (const float*)d_in[0];
    const float* ot     = (const float*)d_in[1];
    const float* ln_e_s = (const float*)d_in[2];
    const float* ln_e_b = (const float*)d_in[3];
    const float* We1    = (const float*)d_in[4];
    const float* be1    = (const float*)d_in[5];
    const float* We2    = (const float*)d_in[6];
    const float* be2    = (const float*)d_in[7];
    const float* ln_a_s = (const float*)d_in[8];
    const float* ln_a_b = (const float*)d_in[9];
    const float* Wa1    = (const float*)d_in[10];
    const float* ba1    = (const float*)d_in[11];
    const float* Wa2    = (const float*)d_in[12];
    const float* ba2    = (const float*)d_in[13];
    float* out = (float*)d_out;

    float* ws      = (float*)d_ws;
    float* add_ws  = ws;                         // 262,144 floats
    float* logits  = ws + 262144;                // 4,194,304 floats
    float* pmaxw   = ws + 262144 + 4194304;      // 262,144 floats (8*512*64)
    float* psumw   = pmaxw + 262144;             // 262,144
    float* rmaxw   = psumw + 262144;             // 512
    float* rinvw   = rmaxw + 512;                // 512
    short* We1T    = (short*)(rinvw + 512);      // 65,536 bf16
    short* We2T    = We1T + 128 * 512;           // 8,192 bf16
    short* addT    = We2T + 64 * 128;            // 262,144 bf16

    hipLaunchKernelGGL(prep_weights_kernel, dim3(288), dim3(256), 0, stream,
                       We1, We2, We1T, We2T);
    hipLaunchKernelGGL(add_path_kernel, dim3(BB * RR), dim3(256), 0, stream,
                       ot, ln_a_s, ln_a_b, Wa1, ba1, Wa2, ba2, add_ws);
    hipLaunchKernelGGL(erase_mfma_kernel, dim3(BB * 256), dim3(512), 0, stream,
                       memory, ln_e_s, ln_e_b, We1T, be1, We2T, be2, logits, pmaxw, psumw);
    hipLaunchKernelGGL(softmax_finalize_kernel, dim3(BB), dim3(256), 0, stream,
                       pmaxw, psumw, rmaxw, rinvw);
    hipLaunchKernelGGL(scale_transpose_kernel, dim3(BB * 8), dim3(256), 0, stream,
                       add_ws, rinvw, addT);
    hipLaunchKernelGGL(apply_mfma_kernel, dim3(BB * 256), dim3(256), 0, stream,
                       memory, logits, addT, rmaxw, out);
}

// Round 10
// 196.317 us; speedup vs baseline: 1.0090x; 1.0090x over previous
//
#include <hip/hip_runtime.h>
#include <hip/hip_bf16.h>
#include <math.h>

#define BB 8
#define MM 8192
#define DD 512
#define RR 64
#define HH 128

typedef __attribute__((ext_vector_type(8))) short bf16x8;
typedef __attribute__((ext_vector_type(4))) short bf16x4;
typedef __attribute__((ext_vector_type(4))) float f32x4;

#define XN_LD 520   // bf16 elems per xn row (512 + 8 pad)
#define H_LD  136   // bf16 elems per h row  (128 + 8 pad)

__device__ __forceinline__ float gelu_tanh(float x) {
    float u = 0.7978845608028654f * (x + 0.044715f * x * x * x);
    float e = __expf(2.0f * u);
    float t = 1.0f - 2.0f / (e + 1.0f);   // tanh(u)
    return 0.5f * x * (1.0f + t);
}

__device__ __forceinline__ short f2bf(float f) {   // round-to-nearest-even bf16
    unsigned int u = __float_as_uint(f);
    unsigned int r = u + 0x7FFFu + ((u >> 16) & 1u);
    return (short)(r >> 16);
}

// ---------------- prep: transpose-convert weights to bf16 [N][K] ----------------
__global__ __launch_bounds__(256) void prep_weights_kernel(
    const float* __restrict__ We1, const float* __restrict__ We2,
    short* __restrict__ We1T, short* __restrict__ We2T)
{
    int idx = blockIdx.x * 256 + threadIdx.x;
    if (idx < 128 * 512) {           // We1T[n][k] = bf16(We1[k][n])
        int n = idx >> 9, k = idx & 511;
        We1T[idx] = f2bf(We1[k * HH + n]);
    } else {
        int j = idx - 128 * 512;
        if (j < 64 * 128) {          // We2T[n][k] = bf16(We2[k][n])
            int n = j >> 7, k = j & 127;
            We2T[j] = f2bf(We2[k * RR + n]);
        }
    }
}

// ---------------- Kernel A: add path (512 rows, tiny, fp32) ----------------
__global__ __launch_bounds__(256) void add_path_kernel(
    const float* __restrict__ ot, const float* __restrict__ scale,
    const float* __restrict__ bias, const float* __restrict__ Wa1,
    const float* __restrict__ ba1, const float* __restrict__ Wa2,
    const float* __restrict__ ba2, float* __restrict__ add_out)
{
    int tid = threadIdx.x;
    int b = blockIdx.x >> 6, r = blockIdx.x & 63;
    const float* x = ot + (size_t)(b * RR + r) * DD;
    __shared__ float xs[DD];
    __shared__ float hsm[HH];
    __shared__ float rs[4], rq[4];
    float v0 = x[tid], v1 = x[tid + 256];
    float s = v0 + v1, q = v0 * v0 + v1 * v1;
    #pragma unroll
    for (int off = 32; off > 0; off >>= 1) { s += __shfl_xor(s, off); q += __shfl_xor(q, off); }
    if ((tid & 63) == 0) { rs[tid >> 6] = s; rq[tid >> 6] = q; }
    __syncthreads();
    s = rs[0] + rs[1] + rs[2] + rs[3];
    q = rq[0] + rq[1] + rq[2] + rq[3];
    float mean = s * (1.0f / DD);
    float var = q * (1.0f / DD) - mean * mean;
    float inv = rsqrtf(var + 1e-6f);
    xs[tid]       = (v0 - mean) * inv * scale[tid]       + bias[tid];
    xs[tid + 256] = (v1 - mean) * inv * scale[tid + 256] + bias[tid + 256];
    __syncthreads();
    if (tid < HH) {
        float acc = ba1[tid];
        for (int k = 0; k < DD; k++) acc = fmaf(xs[k], Wa1[k * HH + tid], acc);
        hsm[tid] = gelu_tanh(acc);
    }
    __syncthreads();
    int d0 = tid, d1 = tid + 256;
    float a0 = ba2[d0], a1 = ba2[d1];
    #pragma unroll 4
    for (int k = 0; k < HH; k++) {
        float hk = hsm[k];
        a0 = fmaf(hk, Wa2[k * DD + d0], a0);
        a1 = fmaf(hk, Wa2[k * DD + d1], a1);
    }
    add_out[(size_t)(b * RR + r) * DD + d0] = a0;
    add_out[(size_t)(b * RR + r) * DD + d1] = a1;
}

// ---------------- erase v5: 8-wave blocks, B-register-prefetch, no-max softmax ------
// Stores exp(logit) to logits buffer; per-16-row column sums to psum.
__global__ __launch_bounds__(512, 4) void erase_mfma_kernel(
    const float* __restrict__ mem, const float* __restrict__ scale,
    const float* __restrict__ bias, const short* __restrict__ We1T,
    const float* __restrict__ be1, const short* __restrict__ We2T,
    const float* __restrict__ be2, float* __restrict__ logits,
    float* __restrict__ psum)
{
    __shared__ short xn[32 * XN_LD];     // 33,280 B; hsm overlays after GEMM1
    short* hsm = xn;

    int tid = threadIdx.x;
    int b = blockIdx.x >> 8;
    int chunk = blockIdx.x & 255;
    int m0 = chunk * 32;

    // ---- LN: 16 threads per row, 8 independent float4 loads per thread ----
    {
        int row = tid >> 4, sub = tid & 15;
        const float4* srcv = (const float4*)(mem + (size_t)(b * MM + m0 + row) * DD);
        float4 v[8];
        #pragma unroll
        for (int j = 0; j < 8; j++) v[j] = srcv[j * 16 + sub];
        float s = 0.f, q = 0.f;
        #pragma unroll
        for (int j = 0; j < 8; j++) {
            s += v[j].x + v[j].y + v[j].z + v[j].w;
            q += v[j].x*v[j].x + v[j].y*v[j].y + v[j].z*v[j].z + v[j].w*v[j].w;
        }
        #pragma unroll
        for (int off = 1; off <= 8; off <<= 1) { s += __shfl_xor(s, off); q += __shfl_xor(q, off); }
        float mean = s * (1.0f / 512.0f);
        float var = q * (1.0f / 512.0f) - mean * mean;
        float inv = rsqrtf(var + 1e-6f);
        const float4* scv = (const float4*)scale;
        const float4* biv = (const float4*)bias;
        #pragma unroll
        for (int j = 0; j < 8; j++) {
            float4 sc = scv[j * 16 + sub], bi = biv[j * 16 + sub];
            bf16x4 o;
            o[0] = f2bf((v[j].x - mean) * inv * sc.x + bi.x);
            o[1] = f2bf((v[j].y - mean) * inv * sc.y + bi.y);
            o[2] = f2bf((v[j].z - mean) * inv * sc.z + bi.z);
            o[3] = f2bf((v[j].w - mean) * inv * sc.w + bi.w);
            *(bf16x4*)&xn[row * XN_LD + (j * 16 + sub) * 4] = o;
        }
    }

    int w = tid >> 6, l = tid & 63;
    int lr = l & 15, g = l >> 4, kg = g * 8;

    // ---- prefetch ALL 16 GEMM1 B-fragments (issued before the barrier; L2) ----
    const short* bp0 = We1T + ((size_t)(w * 16 + lr) << 9) + kg;
    bf16x8 bfr[16];
    #pragma unroll
    for (int ks = 0; ks < 16; ks++) bfr[ks] = *(const bf16x8*)(bp0 + ks * 32);
    __syncthreads();

    // ---- GEMM1: wave w owns col-frag w (cols w*16..+15), rows 0..31 ----
    f32x4 acc0 = {0.f,0.f,0.f,0.f}, acc1 = acc0;
    #pragma unroll
    for (int ks = 0; ks < 16; ks++) {
        int k0 = ks * 32;
        bf16x8 a0 = *(const bf16x8*)&xn[lr * XN_LD + k0 + kg];
        bf16x8 a1 = *(const bf16x8*)&xn[(16 + lr) * XN_LD + k0 + kg];
        acc0 = __builtin_amdgcn_mfma_f32_16x16x32_bf16(a0, bfr[ks], acc0, 0, 0, 0);
        acc1 = __builtin_amdgcn_mfma_f32_16x16x32_bf16(a1, bfr[ks], acc1, 0, 0, 0);
    }
    // ---- prefetch GEMM2 B-fragments (We2T, L1/L2-hot) ----
    int mhalf = w & 1, nf2 = w >> 1;
    const short* bp2 = We2T + (nf2 * 16 + lr) * 128 + kg;
    bf16x8 bfr2[4];
    #pragma unroll
    for (int ks = 0; ks < 4; ks++) bfr2[ks] = *(const bf16x8*)(bp2 + ks * 32);

    __syncthreads();   // WAR: all waves done reading xn before hsm overlay writes
    {
        int col = w * 16 + lr;
        float bv = be1[col];
        #pragma unroll
        for (int rg = 0; rg < 4; rg++) {
            hsm[(g * 4 + rg) * H_LD + col]      = f2bf(gelu_tanh(acc0[rg] + bv));
            hsm[(16 + g * 4 + rg) * H_LD + col] = f2bf(gelu_tanh(acc1[rg] + bv));
        }
    }
    __syncthreads();

    // ---- GEMM2: wave w -> m-half (w&1), col-frag (w>>1) ----
    f32x4 c0 = {0.f,0.f,0.f,0.f};
    #pragma unroll
    for (int ks = 0; ks < 4; ks++) {
        bf16x8 a2 = *(const bf16x8*)&hsm[(mhalf * 16 + lr) * H_LD + ks * 32 + kg];
        c0 = __builtin_amdgcn_mfma_f32_16x16x32_bf16(a2, bfr2[ks], c0, 0, 0, 0);
    }
    // ---- +bias, store exp(logit), per-16-row column sum (no max needed) ----
    {
        int c = nf2 * 16 + lr;
        float bv = be2[c];
        float sm = 0.f;
        #pragma unroll
        for (int rg = 0; rg < 4; rg++) {
            float ev = __expf(c0[rg] + bv);
            sm += ev;
            logits[(size_t)(b * MM + m0 + mhalf * 16 + g * 4 + rg) * 64 + c] = ev;
        }
        sm += __shfl_xor(sm, 16);
        sm += __shfl_xor(sm, 32);
        if (l < 16) {
            int ch2 = chunk * 2 + mhalf;           // 16-row chunk id: 0..511
            psum[((size_t)b * 512 + ch2) * 64 + c] = sm;
        }
    }
}

// ---------------- finalize: rinv = 1/sum, then scale+transpose add -> addT ----------
__global__ __launch_bounds__(256) void softmax_finalize_kernel(
    const float* __restrict__ psum, const float* __restrict__ add,
    float* __restrict__ rinv, short* __restrict__ addT)
{
    int b = blockIdx.x;
    int g = threadIdx.x >> 6, r = threadIdx.x & 63;
    __shared__ float sm_[4][64];
    __shared__ float rinvl[64];
    float sm = 0.0f;
    for (int ch = g; ch < 512; ch += 4)
        sm += psum[((size_t)b * 512 + ch) * 64 + r];
    sm_[g][r] = sm;
    __syncthreads();
    if (threadIdx.x < 64) {
        float S = sm_[0][threadIdx.x] + sm_[1][threadIdx.x]
                + sm_[2][threadIdx.x] + sm_[3][threadIdx.x];
        float rv = 1.0f / S;
        rinv[b * 64 + threadIdx.x] = rv;
        rinvl[threadIdx.x] = rv;
    }
    __syncthreads();
    const float* addb = add + (size_t)b * RR * DD;
    #pragma unroll 8
    for (int i = 0; i < 128; i++) {
        int idx = threadIdx.x + i * 256;          // 0..32767
        int d = idx >> 6, rr = idx & 63;
        addT[(size_t)b * 32768 + idx] = f2bf(addb[(size_t)rr * 512 + d] * rinvl[rr]);
    }
}

// ---------------- apply: w = exp_logit * rinv (no exp in-kernel); MFMA; blend --------
__global__ __launch_bounds__(256, 4) void apply_mfma_kernel(
    const float* __restrict__ mem, const float* __restrict__ logits,
    const short* __restrict__ addT, const float* __restrict__ rinv,
    float* __restrict__ out)
{
    int tid = threadIdx.x;
    int w = tid >> 6, l = tid & 63;
    int b = blockIdx.x >> 8;
    int mt = blockIdx.x & 255;
    int m0 = mt * 32;
    int lr = l & 15, kg = (l >> 4) * 8;
    int nbase = w * 128;
    const short* aT = addT + (size_t)b * 512 * 64;

    float rv0[8], rv1[8];
    #pragma unroll
    for (int j = 0; j < 8; j++) {
        rv0[j] = rinv[b * 64 + kg + j];
        rv1[j] = rinv[b * 64 + 32 + kg + j];
    }

    for (int ms = 0; ms < 2; ms++) {
        // ---- prefetch the 32 mem scalars this lane blends in this ms-iter ----
        float mv[8][4];
        #pragma unroll
        for (int nf = 0; nf < 8; nf++) {
            int d = nbase + nf * 16 + lr;
            #pragma unroll
            for (int rg = 0; rg < 4; rg++) {
                int m = m0 + ms * 16 + (l >> 4) * 4 + rg;
                mv[nf][rg] = mem[(size_t)(b * MM + m) * DD + d];
            }
        }
        // ---- weights: exp_logit * rinv, pack bf16 ----
        int mrow = m0 + ms * 16 + lr;
        const float* lp = logits + (size_t)(b * MM + mrow) * 64 + kg;
        bf16x8 a0, a1;
        #pragma unroll
        for (int j = 0; j < 8; j++) {
            a0[j] = f2bf(lp[j]      * rv0[j]);
            a1[j] = f2bf(lp[32 + j] * rv1[j]);
        }

        f32x4 acc[8];
        #pragma unroll
        for (int nf = 0; nf < 8; nf++) {
            int d = nbase + nf * 16 + lr;
            bf16x8 b0 = *(const bf16x8*)&aT[d * 64 + kg];
            bf16x8 b1 = *(const bf16x8*)&aT[d * 64 + 32 + kg];
            f32x4 c = (f32x4){0.f, 0.f, 0.f, 0.f};
            c = __builtin_amdgcn_mfma_f32_16x16x32_bf16(a0, b0, c, 0, 0, 0);
            c = __builtin_amdgcn_mfma_f32_16x16x32_bf16(a1, b1, c, 0, 0, 0);
            acc[nf] = c;
        }
        // ---- epilogue: out = mem + ea*(1-mem) (mem already in regs) ----
        #pragma unroll
        for (int nf = 0; nf < 8; nf++) {
            int d = nbase + nf * 16 + lr;
            #pragma unroll
            for (int rg = 0; rg < 4; rg++) {
                int m = m0 + ms * 16 + (l >> 4) * 4 + rg;
                size_t off = (size_t)(b * MM + m) * DD + d;
                float mvv = mv[nf][rg];
                out[off] = fmaf(acc[nf][rg], 1.0f - mvv, mvv);
            }
        }
    }
}

extern "C" void kernel_launch(void* const* d_in, const int* in_sizes, int n_in,
                              void* d_out, int out_size, void* d_ws, size_t ws_size,
                              hipStream_t stream) {
    const float* memory = (const float*)d_in[0];
    const float* ot     = (const float*)d_in[1];
    const float* ln_e_s = (const float*)d_in[2];
    const float* ln_e_b = (const float*)d_in[3];
    const float* We1    = (const float*)d_in[4];
    const float* be1    = (const float*)d_in[5];
    const float* We2    = (const float*)d_in[6];
    const float* be2    = (const float*)d_in[7];
    const float* ln_a_s = (const float*)d_in[8];
    const float* ln_a_b = (const float*)d_in[9];
    const float* Wa1    = (const float*)d_in[10];
    const float* ba1    = (const float*)d_in[11];
    const float* Wa2    = (const float*)d_in[12];
    const float* ba2    = (const float*)d_in[13];
    float* out = (float*)d_out;

    float* ws      = (float*)d_ws;
    float* add_ws  = ws;                         // 262,144 floats
    float* logits  = ws + 262144;                // 4,194,304 floats (exp values)
    float* psumw   = ws + 262144 + 4194304;      // 262,144 floats (8*512*64)
    float* rinvw   = psumw + 262144;             // 512
    short* We1T    = (short*)(rinvw + 512);      // 65,536 bf16
    short* We2T    = We1T + 128 * 512;           // 8,192 bf16
    short* addT    = We2T + 64 * 128;            // 262,144 bf16

    hipLaunchKernelGGL(prep_weights_kernel, dim3(288), dim3(256), 0, stream,
                       We1, We2, We1T, We2T);
    hipLaunchKernelGGL(add_path_kernel, dim3(BB * RR), dim3(256), 0, stream,
                       ot, ln_a_s, ln_a_b, Wa1, ba1, Wa2, ba2, add_ws);
    hipLaunchKernelGGL(erase_mfma_kernel, dim3(BB * 256), dim3(512), 0, stream,
                       memory, ln_e_s, ln_e_b, We1T, be1, We2T, be2, logits, psumw);
    hipLaunchKernelGGL(softmax_finalize_kernel, dim3(BB), dim3(256), 0, stream,
                       psumw, add_ws, rinvw, addT);
    hipLaunchKernelGGL(apply_mfma_kernel, dim3(BB * 256), dim3(256), 0, stream,
                       memory, logits, addT, rinvw, out);
}

// Round 11
// 187.753 us; speedup vs baseline: 1.0551x; 1.0456x over previous
//
#include <hip/hip_runtime.h>
#include <hip/hip_bf16.h>
#include <math.h>

#define BB 8
#define MM 8192
#define DD 512
#define RR 64
#define HH 128

typedef __attribute__((ext_vector_type(8))) short bf16x8;
typedef __attribute__((ext_vector_type(4))) short bf16x4;
typedef __attribute__((ext_vector_type(4))) float f32x4;

#define XN_LD 520   // bf16 elems per xn row (512 + 8 pad)
#define H_LD  136   // bf16 elems per h row  (128 + 8 pad)

__device__ __forceinline__ float gelu_tanh(float x) {
    float u = 0.7978845608028654f * (x + 0.044715f * x * x * x);
    float e = __expf(2.0f * u);
    float t = 1.0f - 2.0f / (e + 1.0f);   // tanh(u)
    return 0.5f * x * (1.0f + t);
}

__device__ __forceinline__ short f2bf(float f) {   // round-to-nearest-even bf16
    unsigned int u = __float_as_uint(f);
    unsigned int r = u + 0x7FFFu + ((u >> 16) & 1u);
    return (short)(r >> 16);
}

// ---------------- prep: transpose-convert weights to bf16 [N][K] ----------------
__global__ __launch_bounds__(256) void prep_weights_kernel(
    const float* __restrict__ We1, const float* __restrict__ We2,
    short* __restrict__ We1T, short* __restrict__ We2T)
{
    int idx = blockIdx.x * 256 + threadIdx.x;
    if (idx < 128 * 512) {           // We1T[n][k] = bf16(We1[k][n])
        int n = idx >> 9, k = idx & 511;
        We1T[idx] = f2bf(We1[k * HH + n]);
    } else {
        int j = idx - 128 * 512;
        if (j < 64 * 128) {          // We2T[n][k] = bf16(We2[k][n])
            int n = j >> 7, k = j & 127;
            We2T[j] = f2bf(We2[k * RR + n]);
        }
    }
}

// ---------------- Kernel A: add path (512 rows, tiny, fp32) ----------------
__global__ __launch_bounds__(256) void add_path_kernel(
    const float* __restrict__ ot, const float* __restrict__ scale,
    const float* __restrict__ bias, const float* __restrict__ Wa1,
    const float* __restrict__ ba1, const float* __restrict__ Wa2,
    const float* __restrict__ ba2, float* __restrict__ add_out)
{
    int tid = threadIdx.x;
    int b = blockIdx.x >> 6, r = blockIdx.x & 63;
    const float* x = ot + (size_t)(b * RR + r) * DD;
    __shared__ float xs[DD];
    __shared__ float hsm[HH];
    __shared__ float rs[4], rq[4];
    float v0 = x[tid], v1 = x[tid + 256];
    float s = v0 + v1, q = v0 * v0 + v1 * v1;
    #pragma unroll
    for (int off = 32; off > 0; off >>= 1) { s += __shfl_xor(s, off); q += __shfl_xor(q, off); }
    if ((tid & 63) == 0) { rs[tid >> 6] = s; rq[tid >> 6] = q; }
    __syncthreads();
    s = rs[0] + rs[1] + rs[2] + rs[3];
    q = rq[0] + rq[1] + rq[2] + rq[3];
    float mean = s * (1.0f / DD);
    float var = q * (1.0f / DD) - mean * mean;
    float inv = rsqrtf(var + 1e-6f);
    xs[tid]       = (v0 - mean) * inv * scale[tid]       + bias[tid];
    xs[tid + 256] = (v1 - mean) * inv * scale[tid + 256] + bias[tid + 256];
    __syncthreads();
    if (tid < HH) {
        float acc = ba1[tid];
        for (int k = 0; k < DD; k++) acc = fmaf(xs[k], Wa1[k * HH + tid], acc);
        hsm[tid] = gelu_tanh(acc);
    }
    __syncthreads();
    int d0 = tid, d1 = tid + 256;
    float a0 = ba2[d0], a1 = ba2[d1];
    #pragma unroll 4
    for (int k = 0; k < HH; k++) {
        float hk = hsm[k];
        a0 = fmaf(hk, Wa2[k * DD + d0], a0);
        a1 = fmaf(hk, Wa2[k * DD + d1], a1);
    }
    add_out[(size_t)(b * RR + r) * DD + d0] = a0;
    add_out[(size_t)(b * RR + r) * DD + d1] = a1;
}

// ---------------- erase v6: 4-chunk blocks, B-frag reuse, overlapped next-chunk loads
// Each block: 4 consecutive 32-row chunks. B-fragments loaded ONCE (registers),
// next chunk's mem loads issued before the GEMMs (T14 overlap). No-max softmax.
__global__ __launch_bounds__(512) void erase_mfma_kernel(
    const float* __restrict__ mem, const float* __restrict__ scale,
    const float* __restrict__ bias, const short* __restrict__ We1T,
    const float* __restrict__ be1, const short* __restrict__ We2T,
    const float* __restrict__ be2, float* __restrict__ logits,
    float* __restrict__ psum)
{
    __shared__ short xn[32 * XN_LD];     // 33,280 B; hsm overlays after GEMM1
    short* hsm = xn;

    int tid = threadIdx.x;
    int b = blockIdx.x >> 6;
    int cbase = (blockIdx.x & 63) * 4;   // first 32-row chunk of this block

    int w = tid >> 6, l = tid & 63;
    int lr = l & 15, g = l >> 4, kg = g * 8;
    int row = tid >> 4, sub = tid & 15;
    int mhalf = w & 1, nf2 = w >> 1;

    // ---- B-fragment prefetch, ONCE per block (reused across 4 chunks) ----
    const short* bp0 = We1T + ((size_t)(w * 16 + lr) << 9) + kg;
    bf16x8 bfr[16];
    #pragma unroll
    for (int ks = 0; ks < 16; ks++) bfr[ks] = *(const bf16x8*)(bp0 + ks * 32);
    const short* bp2 = We2T + (nf2 * 16 + lr) * 128 + kg;
    bf16x8 bfr2[4];
    #pragma unroll
    for (int ks = 0; ks < 4; ks++) bfr2[ks] = *(const bf16x8*)(bp2 + ks * 32);

    const float4* scv = (const float4*)scale;
    const float4* biv = (const float4*)bias;

    // ---- load chunk 0 rows ----
    float4 v[8];
    {
        const float4* srcv = (const float4*)(mem + (size_t)(b * MM + cbase * 32 + row) * DD);
        #pragma unroll
        for (int j = 0; j < 8; j++) v[j] = srcv[j * 16 + sub];
    }

    for (int c = 0; c < 4; c++) {
        int m0 = (cbase + c) * 32;

        // ---- LN from v -> xn (16 threads/row) ----
        {
            float s = 0.f, q = 0.f;
            #pragma unroll
            for (int j = 0; j < 8; j++) {
                s += v[j].x + v[j].y + v[j].z + v[j].w;
                q += v[j].x*v[j].x + v[j].y*v[j].y + v[j].z*v[j].z + v[j].w*v[j].w;
            }
            #pragma unroll
            for (int off = 1; off <= 8; off <<= 1) { s += __shfl_xor(s, off); q += __shfl_xor(q, off); }
            float mean = s * (1.0f / 512.0f);
            float var = q * (1.0f / 512.0f) - mean * mean;
            float inv = rsqrtf(var + 1e-6f);
            #pragma unroll
            for (int j = 0; j < 8; j++) {
                float4 sc = scv[j * 16 + sub], bi = biv[j * 16 + sub];
                bf16x4 o;
                o[0] = f2bf((v[j].x - mean) * inv * sc.x + bi.x);
                o[1] = f2bf((v[j].y - mean) * inv * sc.y + bi.y);
                o[2] = f2bf((v[j].z - mean) * inv * sc.z + bi.z);
                o[3] = f2bf((v[j].w - mean) * inv * sc.w + bi.w);
                *(bf16x4*)&xn[row * XN_LD + (j * 16 + sub) * 4] = o;
            }
        }
        __syncthreads();

        // ---- issue NEXT chunk's loads (overlap with both GEMMs) ----
        if (c < 3) {
            const float4* srcv = (const float4*)(mem + (size_t)(b * MM + m0 + 32 + row) * DD);
            #pragma unroll
            for (int j = 0; j < 8; j++) v[j] = srcv[j * 16 + sub];
        }

        // ---- GEMM1: wave w owns cols w*16..+15, rows 0..31 ----
        f32x4 acc0 = {0.f,0.f,0.f,0.f}, acc1 = acc0;
        #pragma unroll
        for (int ks = 0; ks < 16; ks++) {
            int k0 = ks * 32;
            bf16x8 a0 = *(const bf16x8*)&xn[lr * XN_LD + k0 + kg];
            bf16x8 a1 = *(const bf16x8*)&xn[(16 + lr) * XN_LD + k0 + kg];
            acc0 = __builtin_amdgcn_mfma_f32_16x16x32_bf16(a0, bfr[ks], acc0, 0, 0, 0);
            acc1 = __builtin_amdgcn_mfma_f32_16x16x32_bf16(a1, bfr[ks], acc1, 0, 0, 0);
        }
        __syncthreads();   // WAR: all waves done reading xn before hsm overlay writes
        {
            int col = w * 16 + lr;
            float bv = be1[col];
            #pragma unroll
            for (int rg = 0; rg < 4; rg++) {
                hsm[(g * 4 + rg) * H_LD + col]      = f2bf(gelu_tanh(acc0[rg] + bv));
                hsm[(16 + g * 4 + rg) * H_LD + col] = f2bf(gelu_tanh(acc1[rg] + bv));
            }
        }
        __syncthreads();

        // ---- GEMM2: wave w -> m-half (w&1), col-frag (w>>1) ----
        f32x4 c0 = {0.f,0.f,0.f,0.f};
        #pragma unroll
        for (int ks = 0; ks < 4; ks++) {
            bf16x8 a2 = *(const bf16x8*)&hsm[(mhalf * 16 + lr) * H_LD + ks * 32 + kg];
            c0 = __builtin_amdgcn_mfma_f32_16x16x32_bf16(a2, bfr2[ks], c0, 0, 0, 0);
        }
        // ---- +bias, store exp(logit), per-16-row column sum ----
        {
            int cc = nf2 * 16 + lr;
            float bv = be2[cc];
            float sm = 0.f;
            #pragma unroll
            for (int rg = 0; rg < 4; rg++) {
                float ev = __expf(c0[rg] + bv);
                sm += ev;
                logits[(size_t)(b * MM + m0 + mhalf * 16 + g * 4 + rg) * 64 + cc] = ev;
            }
            sm += __shfl_xor(sm, 16);
            sm += __shfl_xor(sm, 32);
            if (l < 16) {
                int ch2 = (m0 >> 4) + mhalf;       // 16-row chunk id: 0..511
                psum[((size_t)b * 512 + ch2) * 64 + cc] = sm;
            }
        }
        __syncthreads();   // WAR: GEMM2/hsm reads done before next LN writes xn
    }
}

// ---------------- finalize: rinv = 1/sum, then scale+transpose add -> addT ----------
__global__ __launch_bounds__(256) void softmax_finalize_kernel(
    const float* __restrict__ psum, const float* __restrict__ add,
    float* __restrict__ rinv, short* __restrict__ addT)
{
    int b = blockIdx.x;
    int g = threadIdx.x >> 6, r = threadIdx.x & 63;
    __shared__ float sm_[4][64];
    __shared__ float rinvl[64];
    float sm = 0.0f;
    for (int ch = g; ch < 512; ch += 4)
        sm += psum[((size_t)b * 512 + ch) * 64 + r];
    sm_[g][r] = sm;
    __syncthreads();
    if (threadIdx.x < 64) {
        float S = sm_[0][threadIdx.x] + sm_[1][threadIdx.x]
                + sm_[2][threadIdx.x] + sm_[3][threadIdx.x];
        float rv = 1.0f / S;
        rinv[b * 64 + threadIdx.x] = rv;
        rinvl[threadIdx.x] = rv;
    }
    __syncthreads();
    const float* addb = add + (size_t)b * RR * DD;
    #pragma unroll 8
    for (int i = 0; i < 128; i++) {
        int idx = threadIdx.x + i * 256;          // 0..32767
        int d = idx >> 6, rr = idx & 63;
        addT[(size_t)b * 32768 + idx] = f2bf(addb[(size_t)rr * 512 + d] * rinvl[rr]);
    }
}

// ---------------- apply: w = exp_logit * rinv; MFMA; blend (R10-validated) ----------
__global__ __launch_bounds__(256, 4) void apply_mfma_kernel(
    const float* __restrict__ mem, const float* __restrict__ logits,
    const short* __restrict__ addT, const float* __restrict__ rinv,
    float* __restrict__ out)
{
    int tid = threadIdx.x;
    int w = tid >> 6, l = tid & 63;
    int b = blockIdx.x >> 8;
    int mt = blockIdx.x & 255;
    int m0 = mt * 32;
    int lr = l & 15, kg = (l >> 4) * 8;
    int nbase = w * 128;
    const short* aT = addT + (size_t)b * 512 * 64;

    float rv0[8], rv1[8];
    #pragma unroll
    for (int j = 0; j < 8; j++) {
        rv0[j] = rinv[b * 64 + kg + j];
        rv1[j] = rinv[b * 64 + 32 + kg + j];
    }

    for (int ms = 0; ms < 2; ms++) {
        // ---- prefetch the 32 mem scalars this lane blends in this ms-iter ----
        float mv[8][4];
        #pragma unroll
        for (int nf = 0; nf < 8; nf++) {
            int d = nbase + nf * 16 + lr;
            #pragma unroll
            for (int rg = 0; rg < 4; rg++) {
                int m = m0 + ms * 16 + (l >> 4) * 4 + rg;
                mv[nf][rg] = mem[(size_t)(b * MM + m) * DD + d];
            }
        }
        // ---- weights: exp_logit * rinv, pack bf16 ----
        int mrow = m0 + ms * 16 + lr;
        const float* lp = logits + (size_t)(b * MM + mrow) * 64 + kg;
        bf16x8 a0, a1;
        #pragma unroll
        for (int j = 0; j < 8; j++) {
            a0[j] = f2bf(lp[j]      * rv0[j]);
            a1[j] = f2bf(lp[32 + j] * rv1[j]);
        }

        f32x4 acc[8];
        #pragma unroll
        for (int nf = 0; nf < 8; nf++) {
            int d = nbase + nf * 16 + lr;
            bf16x8 b0 = *(const bf16x8*)&aT[d * 64 + kg];
            bf16x8 b1 = *(const bf16x8*)&aT[d * 64 + 32 + kg];
            f32x4 c = (f32x4){0.f, 0.f, 0.f, 0.f};
            c = __builtin_amdgcn_mfma_f32_16x16x32_bf16(a0, b0, c, 0, 0, 0);
            c = __builtin_amdgcn_mfma_f32_16x16x32_bf16(a1, b1, c, 0, 0, 0);
            acc[nf] = c;
        }
        // ---- epilogue: out = mem + ea*(1-mem) (mem already in regs) ----
        #pragma unroll
        for (int nf = 0; nf < 8; nf++) {
            int d = nbase + nf * 16 + lr;
            #pragma unroll
            for (int rg = 0; rg < 4; rg++) {
                int m = m0 + ms * 16 + (l >> 4) * 4 + rg;
                size_t off = (size_t)(b * MM + m) * DD + d;
                float mvv = mv[nf][rg];
                out[off] = fmaf(acc[nf][rg], 1.0f - mvv, mvv);
            }
        }
    }
}

extern "C" void kernel_launch(void* const* d_in, const int* in_sizes, int n_in,
                              void* d_out, int out_size, void* d_ws, size_t ws_size,
                              hipStream_t stream) {
    const float* memory = (const float*)d_in[0];
    const float* ot     = (const float*)d_in[1];
    const float* ln_e_s = (const float*)d_in[2];
    const float* ln_e_b = (const float*)d_in[3];
    const float* We1    = (const float*)d_in[4];
    const float* be1    = (const float*)d_in[5];
    const float* We2    = (const float*)d_in[6];
    const float* be2    = (const float*)d_in[7];
    const float* ln_a_s = (const float*)d_in[8];
    const float* ln_a_b = (const float*)d_in[9];
    const float* Wa1    = (const float*)d_in[10];
    const float* ba1    = (const float*)d_in[11];
    const float* Wa2    = (const float*)d_in[12];
    const float* ba2    = (const float*)d_in[13];
    float* out = (float*)d_out;

    float* ws      = (float*)d_ws;
    float* add_ws  = ws;                         // 262,144 floats
    float* logits  = ws + 262144;                // 4,194,304 floats (exp values)
    float* psumw   = ws + 262144 + 4194304;      // 262,144 floats (8*512*64)
    float* rinvw   = psumw + 262144;             // 512
    short* We1T    = (short*)(rinvw + 512);      // 65,536 bf16
    short* We2T    = We1T + 128 * 512;           // 8,192 bf16
    short* addT    = We2T + 64 * 128;            // 262,144 bf16

    hipLaunchKernelGGL(prep_weights_kernel, dim3(288), dim3(256), 0, stream,
                       We1, We2, We1T, We2T);
    hipLaunchKernelGGL(add_path_kernel, dim3(BB * RR), dim3(256), 0, stream,
                       ot, ln_a_s, ln_a_b, Wa1, ba1, Wa2, ba2, add_ws);
    hipLaunchKernelGGL(erase_mfma_kernel, dim3(BB * 64), dim3(512), 0, stream,
                       memory, ln_e_s, ln_e_b, We1T, be1, We2T, be2, logits, psumw);
    hipLaunchKernelGGL(softmax_finalize_kernel, dim3(BB), dim3(256), 0, stream,
                       psumw, add_ws, rinvw, addT);
    hipLaunchKernelGGL(apply_mfma_kernel, dim3(BB * 256), dim3(256), 0, stream,
                       memory, logits, addT, rinvw, out);
}